// Round 1
// baseline (1398.396 us; speedup 1.0000x reference)
//
#include <hip/hip_runtime.h>

#define NF 256   // num_features
#define NH 64    // hidden dim
#define NL 3     // hidden-to-hidden layers (DEPTH-2)
#define BT 128   // threads per block = batch tile

// One block = one feature x 128 batch rows. Weights are block-uniform ->
// compiler should emit s_load (SGPR broadcast), keeping VALU as the only
// hot pipe. h lives in a conflict-free [j][tid] LDS buffer (bank=tid%32,
// 2 lanes/bank = free). Each thread touches only its own tid column ->
// no __syncthreads needed anywhere.
__global__ __launch_bounds__(BT) void permlp_kernel(
    const float* __restrict__ x,
    const float* __restrict__ W1,
    const float* __restrict__ b1,
    const float* __restrict__ Wh,
    const float* __restrict__ bh,
    const float* __restrict__ Wo,
    const float* __restrict__ bo,
    float* __restrict__ out)
{
    __shared__ float hbuf[NH][BT];
    const int f   = blockIdx.x;
    const int tid = threadIdx.x;
    const int b   = blockIdx.y * BT + tid;

    // ---- first layer: scalar -> hidden ----
    const float xv = x[(size_t)b * NF + f];
    const float* __restrict__ W1f = W1 + f * NH;
    const float* __restrict__ b1f = b1 + f * NH;
#pragma unroll
    for (int j = 0; j < NH; ++j)
        hbuf[j][tid] = fmaf(xv, W1f[j], b1f[j]);   // store RAW h; relu at read

    // ---- hidden layers ----
    for (int l = 0; l < NL; ++l) {
        const float* __restrict__ Wl = Wh + (((size_t)l * NF + f) * NH) * NH;
        const float* __restrict__ bl = bh + ((size_t)l * NF + f) * NH;
        float acc[NH];
#pragma unroll
        for (int k = 0; k < NH; ++k) acc[k] = bl[k];
#pragma unroll 2
        for (int j = 0; j < NH; ++j) {
            const float hj = fmaxf(hbuf[j][tid], 0.0f);
            const float* __restrict__ wrow = Wl + j * NH;   // uniform -> s_load
#pragma unroll
            for (int k = 0; k < NH; ++k)
                acc[k] = fmaf(hj, wrow[k], acc[k]);         // v_fma with SGPR src
        }
#pragma unroll
        for (int k = 0; k < NH; ++k) hbuf[k][tid] = acc[k]; // raw h for next layer
    }

    // ---- output layer: hidden -> scalar, then sum over features ----
    const float* __restrict__ Wof = Wo + f * NH;
    float s0 = 0.f, s1 = 0.f, s2 = 0.f, s3 = 0.f;
#pragma unroll
    for (int j = 0; j < NH; j += 4) {
        s0 = fmaf(fmaxf(hbuf[j + 0][tid], 0.f), Wof[j + 0], s0);
        s1 = fmaf(fmaxf(hbuf[j + 1][tid], 0.f), Wof[j + 1], s1);
        s2 = fmaf(fmaxf(hbuf[j + 2][tid], 0.f), Wof[j + 2], s2);
        s3 = fmaf(fmaxf(hbuf[j + 3][tid], 0.f), Wof[j + 3], s3);
    }
    const float feats = ((s0 + s1) + (s2 + s3)) + bo[f];
    atomicAdd(&out[b], feats);   // 256 adds per element; noise << 2.1e-2 threshold
}

extern "C" void kernel_launch(void* const* d_in, const int* in_sizes, int n_in,
                              void* d_out, int out_size, void* d_ws, size_t ws_size,
                              hipStream_t stream)
{
    const float* x  = (const float*)d_in[0];
    const float* W1 = (const float*)d_in[1];
    const float* b1 = (const float*)d_in[2];
    const float* Wh = (const float*)d_in[3];
    const float* bh = (const float*)d_in[4];
    const float* Wo = (const float*)d_in[5];
    const float* bo = (const float*)d_in[6];
    float* out = (float*)d_out;

    const int B = in_sizes[0] / NF;   // 16384

    // harness poisons d_out once and never re-poisons between replays:
    // zero it ourselves every call (atomicAdd accumulates into it).
    hipMemsetAsync(out, 0, (size_t)out_size * sizeof(float), stream);

    dim3 grid(NF, B / BT);
    permlp_kernel<<<grid, dim3(BT), 0, stream>>>(x, W1, b1, Wh, bh, Wo, bo, out);
}

// Round 2
// 770.942 us; speedup vs baseline: 1.8139x; 1.8139x over previous
//
#include <hip/hip_runtime.h>

typedef _Float16 f16;
typedef f16  f16x8 __attribute__((ext_vector_type(8)));
typedef float f32x4 __attribute__((ext_vector_type(4)));

#define NF 256   // features
#define NH 64    // hidden dim
#define NL 3     // hidden-to-hidden layers
#define MT 128   // batch rows per block
#define NTHR 512 // 8 waves

// f16-unit index into a [rows][64] f16 plane with XOR bank swizzle.
// byte ^= ((r&7)<<4)  ->  f16-unit ^= ((r&7)<<3). Keeps 16B alignment.
__device__ __forceinline__ int swz(int r, int c) {
    return (r * NH + c) ^ ((r & 7) << 3);
}

__global__ __launch_bounds__(NTHR, 4) void permlp_mfma(
    const float* __restrict__ x,
    const float* __restrict__ W1,
    const float* __restrict__ b1,
    const float* __restrict__ Wh,
    const float* __restrict__ bh,
    const float* __restrict__ Wo,
    const float* __restrict__ bo,
    float* __restrict__ out)
{
    // LDS: 16K + 16K + 24K + 24K = 80 KB exactly -> 2 blocks/CU
    __shared__ __align__(16) f16 hhi[MT * NH];
    __shared__ __align__(16) f16 hlo[MT * NH];
    __shared__ __align__(16) f16 whi[NL][NH * NH];  // Wt[n][k] = W[k][n], fp16 hi
    __shared__ __align__(16) f16 wlo[NL][NH * NH];  // fp16 residual

    const int f   = blockIdx.x;
    const int tid = threadIdx.x;
    const int wv  = tid >> 6;    // wave 0..7, owns rows [wv*16, wv*16+16)
    const int ln  = tid & 63;
    const int b0  = blockIdx.y * MT;
    const int cl  = ln & 15;     // col-lane
    const int gr  = ln >> 4;     // k-group / row-group

    // ---- per-lane epilogue constants from global (L2-resident, hoisted) ----
    float biasv[NL][4];
#pragma unroll
    for (int l = 0; l < NL; ++l)
#pragma unroll
        for (int nt = 0; nt < 4; ++nt)
            biasv[l][nt] = bh[((size_t)l * NF + f) * NH + nt * 16 + cl];
    float wov[4];
#pragma unroll
    for (int nt = 0; nt < 4; ++nt)
        wov[nt] = Wo[f * NH + nt * 16 + cl];
    const float bof = bo[f];

    // ---- stage W: transpose + fp16 hi/lo split ----
    {
        const int hh = tid >> 3;        // input index 0..63
        const int k0 = (tid & 7) * 8;   // output index start
        for (int l = 0; l < NL; ++l) {
            const float* src = Wh + (((size_t)l * NF + f) * NH + hh) * NH + k0;
#pragma unroll
            for (int i = 0; i < 8; ++i) {
                float v = src[i];
                f16 hi = (f16)v;
                whi[l][swz(k0 + i, hh)] = hi;                 // transposed store
                wlo[l][swz(k0 + i, hh)] = (f16)(v - (float)hi);
            }
        }
    }
    __syncthreads();   // the only barrier: W planes become read-only

    // ---- layer 1 (fp32 VALU, wave-private rows) ----
    {
        const int r  = wv * 16 + cl;
        const int j0 = gr * 16;
        const float xv = x[(size_t)(b0 + r) * NF + f];
        const float* w1f = W1 + f * NH + j0;
        const float* b1f = b1 + f * NH + j0;
        f16x8 h0, h1v, l0v, l1v;
#pragma unroll
        for (int jj = 0; jj < 8; ++jj) {
            float v = fmaxf(fmaf(xv, w1f[jj], b1f[jj]), 0.f);
            f16 hi = (f16)v;
            h0[jj] = hi; l0v[jj] = (f16)(v - (float)hi);
        }
#pragma unroll
        for (int jj = 0; jj < 8; ++jj) {
            float v = fmaxf(fmaf(xv, w1f[8 + jj], b1f[8 + jj]), 0.f);
            f16 hi = (f16)v;
            h1v[jj] = hi; l1v[jj] = (f16)(v - (float)hi);
        }
        *(f16x8*)&hhi[swz(r, j0)]     = h0;
        *(f16x8*)&hhi[swz(r, j0 + 8)] = h1v;
        *(f16x8*)&hlo[swz(r, j0)]     = l0v;
        *(f16x8*)&hlo[swz(r, j0 + 8)] = l1v;
    }
    // no barrier needed: each wave reads only its own 16 rows below

    // ---- hidden layers via MFMA (split-3: exact to ~2^-22) ----
    const int ar = wv * 16 + cl;
    for (int l = 0; l < NL; ++l) {
        f16x8 ahi[2], alo[2];
#pragma unroll
        for (int ks = 0; ks < 2; ++ks) {
            const int kk = ks * 32 + gr * 8;
            ahi[ks] = *(const f16x8*)&hhi[swz(ar, kk)];
            alo[ks] = *(const f16x8*)&hlo[swz(ar, kk)];
        }
        f32x4 acc[4];
#pragma unroll
        for (int nt = 0; nt < 4; ++nt) {
            f32x4 z{0.f, 0.f, 0.f, 0.f};
            acc[nt] = z;
        }
#pragma unroll
        for (int nt = 0; nt < 4; ++nt) {
            const int n = nt * 16 + cl;
#pragma unroll
            for (int ks = 0; ks < 2; ++ks) {
                const int kk = ks * 32 + gr * 8;
                f16x8 bh_ = *(const f16x8*)&whi[l][swz(n, kk)];
                f16x8 bl_ = *(const f16x8*)&wlo[l][swz(n, kk)];
                acc[nt] = __builtin_amdgcn_mfma_f32_16x16x32_f16(ahi[ks], bh_, acc[nt], 0, 0, 0);
                acc[nt] = __builtin_amdgcn_mfma_f32_16x16x32_f16(alo[ks], bh_, acc[nt], 0, 0, 0);
                acc[nt] = __builtin_amdgcn_mfma_f32_16x16x32_f16(ahi[ks], bl_, acc[nt], 0, 0, 0);
            }
        }

        if (l < NL - 1) {
            // epilogue: bias -> relu -> split -> store (own rows only)
#pragma unroll
            for (int nt = 0; nt < 4; ++nt) {
                const float bb = biasv[l][nt];
#pragma unroll
                for (int i = 0; i < 4; ++i) {
                    const int rr = wv * 16 + gr * 4 + i;
                    const int cc = nt * 16 + cl;
                    float v = fmaxf(acc[nt][i] + bb, 0.f);
                    f16 hi = (f16)v;
                    hhi[swz(rr, cc)] = hi;
                    hlo[swz(rr, cc)] = (f16)(v - (float)hi);
                }
            }
        } else {
            // output layer fused from registers: relu -> dot Wo -> row-reduce
            float s[4] = {0.f, 0.f, 0.f, 0.f};
#pragma unroll
            for (int nt = 0; nt < 4; ++nt) {
                const float bb = biasv[l][nt];
#pragma unroll
                for (int i = 0; i < 4; ++i)
                    s[i] = fmaf(fmaxf(acc[nt][i] + bb, 0.f), wov[nt], s[i]);
            }
#pragma unroll
            for (int m = 1; m < 16; m <<= 1)
#pragma unroll
                for (int i = 0; i < 4; ++i)
                    s[i] += __shfl_xor(s[i], m, 64);
            if (cl == 0) {
#pragma unroll
                for (int i = 0; i < 4; ++i)
                    atomicAdd(&out[b0 + wv * 16 + gr * 4 + i], s[i] + bof);
            }
        }
    }
}

extern "C" void kernel_launch(void* const* d_in, const int* in_sizes, int n_in,
                              void* d_out, int out_size, void* d_ws, size_t ws_size,
                              hipStream_t stream)
{
    const float* x  = (const float*)d_in[0];
    const float* W1 = (const float*)d_in[1];
    const float* b1 = (const float*)d_in[2];
    const float* Wh = (const float*)d_in[3];
    const float* bh = (const float*)d_in[4];
    const float* Wo = (const float*)d_in[5];
    const float* bo = (const float*)d_in[6];
    float* out = (float*)d_out;

    const int B = in_sizes[0] / NF;   // 16384

    hipMemsetAsync(out, 0, (size_t)out_size * sizeof(float), stream);

    dim3 grid(NF, B / MT);
    permlp_mfma<<<grid, dim3(NTHR), 0, stream>>>(x, W1, b1, Wh, bh, Wo, bo, out);
}

// Round 3
// 668.288 us; speedup vs baseline: 2.0925x; 1.1536x over previous
//
#include <hip/hip_runtime.h>

typedef _Float16 f16;
typedef f16   f16x8 __attribute__((ext_vector_type(8)));
typedef float f32x4 __attribute__((ext_vector_type(4)));

#define NF 256      // features
#define NH 64       // hidden dim
#define NL 3        // hidden-to-hidden layers
#define WROWS 64    // batch rows per wave (4 subtiles of 16)
#define NWAVE 4
#define MT (WROWS * NWAVE)   // 256 rows per block
#define NTHR (NWAVE * 64)

// f32-unit swizzled index into the h plane [MT][NH].
// XOR flips bits 2-4 of the column -> moves in 16B units: keeps f32x4
// chunks contiguous, spreads the stride-256B row pattern across banks.
__device__ __forceinline__ int hswz(int r, int c) {
    return r * NH + (c ^ ((r & 7) << 2));
}

__global__ __launch_bounds__(NTHR, 2) void permlp_v3(
    const float* __restrict__ x,
    const float* __restrict__ W1,
    const float* __restrict__ b1,
    const float* __restrict__ Wh,
    const float* __restrict__ bh,
    const float* __restrict__ Wo,
    const float* __restrict__ bo,
    float* __restrict__ out)
{
    __shared__ float hbuf[MT * NH];   // 64 KB -> 2 blocks/CU

    const int f   = blockIdx.x;
    const int tid = threadIdx.x;
    const int wv  = tid >> 6;
    const int ln  = tid & 63;
    const int cl  = ln & 15;     // fragment col/row lane
    const int gr  = ln >> 4;     // k-group
    const int lr0 = wv * WROWS;              // wave's LDS row base
    const int gb0 = blockIdx.y * MT + lr0;   // wave's global row base

    // ---- layer 1: h1 = relu(x*W1 + b1), one row per lane, f32 -> LDS ----
    {
        const float xv = x[(size_t)(gb0 + ln) * NF + f];
        const float* __restrict__ w1 = W1 + f * NH;   // block-uniform -> s_load
        const float* __restrict__ bb = b1 + f * NH;
#pragma unroll
        for (int c4 = 0; c4 < NH / 4; ++c4) {
            f32x4 v;
#pragma unroll
            for (int j = 0; j < 4; ++j)
                v[j] = fmaxf(fmaf(xv, w1[c4 * 4 + j], bb[c4 * 4 + j]), 0.f);
            *(f32x4*)&hbuf[hswz(lr0 + ln, c4 * 4)] = v;
        }
    }
    // h rows are wave-private: NO barriers anywhere in this kernel.

    // ---- hidden layers: W fragments in registers (global gather), ----
    // ---- h round-trips LDS in f32, split to f16 hi/lo at read.     ----
    for (int l = 0; l < NL; ++l) {
        const float* __restrict__ Wl = Wh + (size_t)(l * NF + f) * NH * NH;
        // B-fragment gather: lane holds Wt[n][k..k+8] = W[k..k+8][n]
        f16x8 bhi[4][2], blo[4][2];   // [nt][ks]
#pragma unroll
        for (int nt = 0; nt < 4; ++nt)
#pragma unroll
            for (int ks = 0; ks < 2; ++ks) {
                const int n  = nt * 16 + cl;
                const int kb = ks * 32 + gr * 8;
                const float* __restrict__ col = Wl + (size_t)kb * NH + n;
                f16x8 hi8, lo8;
#pragma unroll
                for (int j = 0; j < 8; ++j) {
                    float v = col[(size_t)j * NH];
                    f16 h = (f16)v;
                    hi8[j] = h;
                    lo8[j] = (f16)(v - (float)h);
                }
                bhi[nt][ks] = hi8;
                blo[nt][ks] = lo8;
            }
        float biasl[4];
#pragma unroll
        for (int nt = 0; nt < 4; ++nt)
            biasl[nt] = bh[(size_t)(l * NF + f) * NH + nt * 16 + cl];

#pragma unroll
        for (int st = 0; st < 4; ++st) {
            const int m0 = lr0 + st * 16;
            const int m  = m0 + cl;
            // A-fragments: read f32 h (already relu'd), split hi/lo
            f16x8 ahi[2], alo[2];
#pragma unroll
            for (int ks = 0; ks < 2; ++ks) {
                const int k0 = ks * 32 + gr * 8;
                f32x4 a0 = *(const f32x4*)&hbuf[hswz(m, k0)];
                f32x4 a1 = *(const f32x4*)&hbuf[hswz(m, k0 + 4)];
                f16x8 hi8, lo8;
#pragma unroll
                for (int j = 0; j < 4; ++j) {
                    f16 h = (f16)a0[j];
                    hi8[j] = h; lo8[j] = (f16)(a0[j] - (float)h);
                }
#pragma unroll
                for (int j = 0; j < 4; ++j) {
                    f16 h = (f16)a1[j];
                    hi8[4 + j] = h; lo8[4 + j] = (f16)(a1[j] - (float)h);
                }
                ahi[ks] = hi8; alo[ks] = lo8;
            }
            f32x4 acc[4];
#pragma unroll
            for (int nt = 0; nt < 4; ++nt) {
                f32x4 z{0.f, 0.f, 0.f, 0.f};
                acc[nt] = z;
            }
#pragma unroll
            for (int nt = 0; nt < 4; ++nt)
#pragma unroll
                for (int ks = 0; ks < 2; ++ks) {
                    acc[nt] = __builtin_amdgcn_mfma_f32_16x16x32_f16(ahi[ks], bhi[nt][ks], acc[nt], 0, 0, 0);
                    acc[nt] = __builtin_amdgcn_mfma_f32_16x16x32_f16(alo[ks], bhi[nt][ks], acc[nt], 0, 0, 0);
                    acc[nt] = __builtin_amdgcn_mfma_f32_16x16x32_f16(ahi[ks], blo[nt][ks], acc[nt], 0, 0, 0);
                }
            // epilogue: store relu(acc + bias) back as f32 (post-relu h)
#pragma unroll
            for (int nt = 0; nt < 4; ++nt) {
                const float bb = biasl[nt];
#pragma unroll
                for (int i = 0; i < 4; ++i)
                    hbuf[hswz(m0 + gr * 4 + i, nt * 16 + cl)] =
                        fmaxf(acc[nt][i] + bb, 0.f);
            }
        }
    }

    // ---- output layer as a 4th MFMA layer: B = broadcast Wo ----
    {
        f16x8 wohi[2], wolo[2];
#pragma unroll
        for (int ks = 0; ks < 2; ++ks) {
            const int kb = ks * 32 + gr * 8;
            f16x8 hi8, lo8;
#pragma unroll
            for (int j = 0; j < 8; ++j) {
                float v = Wo[f * NH + kb + j];
                f16 h = (f16)v;
                hi8[j] = h;
                lo8[j] = (f16)(v - (float)h);
            }
            wohi[ks] = hi8; wolo[ks] = lo8;
        }
        const float bof = bo[f];
#pragma unroll
        for (int st = 0; st < 4; ++st) {
            const int m0 = lr0 + st * 16;
            const int m  = m0 + cl;
            f16x8 ahi[2], alo[2];
#pragma unroll
            for (int ks = 0; ks < 2; ++ks) {
                const int k0 = ks * 32 + gr * 8;
                f32x4 a0 = *(const f32x4*)&hbuf[hswz(m, k0)];
                f32x4 a1 = *(const f32x4*)&hbuf[hswz(m, k0 + 4)];
                f16x8 hi8, lo8;
#pragma unroll
                for (int j = 0; j < 4; ++j) {
                    f16 h = (f16)a0[j];
                    hi8[j] = h; lo8[j] = (f16)(a0[j] - (float)h);
                }
#pragma unroll
                for (int j = 0; j < 4; ++j) {
                    f16 h = (f16)a1[j];
                    hi8[4 + j] = h; lo8[4 + j] = (f16)(a1[j] - (float)h);
                }
                ahi[ks] = hi8; alo[ks] = lo8;
            }
            f32x4 a2{0.f, 0.f, 0.f, 0.f};
#pragma unroll
            for (int ks = 0; ks < 2; ++ks) {
                a2 = __builtin_amdgcn_mfma_f32_16x16x32_f16(ahi[ks], wohi[ks], a2, 0, 0, 0);
                a2 = __builtin_amdgcn_mfma_f32_16x16x32_f16(alo[ks], wohi[ks], a2, 0, 0, 0);
                a2 = __builtin_amdgcn_mfma_f32_16x16x32_f16(ahi[ks], wolo[ks], a2, 0, 0, 0);
            }
            // all 16 cols hold the same feats value; lane cl==0 commits
            if (cl == 0) {
#pragma unroll
                for (int i = 0; i < 4; ++i)
                    atomicAdd(&out[gb0 + st * 16 + gr * 4 + i], a2[i] + bof);
            }
        }
    }
}

extern "C" void kernel_launch(void* const* d_in, const int* in_sizes, int n_in,
                              void* d_out, int out_size, void* d_ws, size_t ws_size,
                              hipStream_t stream)
{
    const float* x  = (const float*)d_in[0];
    const float* W1 = (const float*)d_in[1];
    const float* b1 = (const float*)d_in[2];
    const float* Wh = (const float*)d_in[3];
    const float* bh = (const float*)d_in[4];
    const float* Wo = (const float*)d_in[5];
    const float* bo = (const float*)d_in[6];
    float* out = (float*)d_out;

    const int B = in_sizes[0] / NF;   // 16384

    hipMemsetAsync(out, 0, (size_t)out_size * sizeof(float), stream);

    dim3 grid(NF, B / MT);
    permlp_v3<<<grid, dim3(NTHR), 0, stream>>>(x, W1, b1, Wh, bh, Wo, bo, out);
}